// Round 2
// baseline (470.694 us; speedup 1.0000x reference)
//
#include <hip/hip_runtime.h>
#include <math.h>

#define N_TOK 4096
#define C_CH  64
#define HW    256
#define E_EXP 16
#define CCAP  384
#define NEC   (N_TOK * E_EXP * CCAP)   // 25,165,824 elements per tensor

// ws layout (float words):
//   [0, 64)            : z-loss partial slots
//   [64, 64+1024)      : prob-sum partial slots, [e*64 + slot]
//   [1088, 1088+4096)  : expert_gate per token (float)
//   [5184, 5184+4096)  : expert_index per token (int)

__global__ __launch_bounds__(256) void k_zero(float* __restrict__ out, float* __restrict__ ws) {
    float4* o4 = (float4*)out;
    const long long n4 = (2LL * NEC) / 4;   // 12,582,912 float4s
    long long i = (long long)blockIdx.x * blockDim.x + threadIdx.x;
    const long long stride = (long long)gridDim.x * blockDim.x;
    const float4 z = {0.f, 0.f, 0.f, 0.f};
    for (; i < n4; i += stride) o4[i] = z;
    if (blockIdx.x == 0) {
        for (int j = threadIdx.x; j < 1088; j += blockDim.x) ws[j] = 0.f;
    }
}

__global__ __launch_bounds__(256) void k_router(const float* __restrict__ X,
                                                const float* __restrict__ Wg,
                                                const float* __restrict__ bg,
                                                float* __restrict__ ws) {
    __shared__ float Wl[C_CH * E_EXP];      // 4 KB
    __shared__ float waveacc[4][E_EXP];

    const int t = threadIdx.x;
    const int n = blockIdx.x;
    for (int j = t; j < C_CH * E_EXP; j += 256) Wl[j] = Wg[j];
    __syncthreads();

    const int w = t >> 6, lane = t & 63;
    const float4* Xv = (const float4*)(X + (long long)n * (C_CH * HW));

    float acc[E_EXP];
#pragma unroll
    for (int e = 0; e < E_EXP; ++e) acc[e] = 0.f;

    // iteration k: wave w reads channel c = 4k+w, 64 float4s coalesced (1 KB/instr)
#pragma unroll
    for (int k = 0; k < 16; ++k) {
        float4 v = Xv[k * 256 + w * 64 + lane];
        float s = (v.x + v.y) + (v.z + v.w);
        const int c = k * 4 + w;
#pragma unroll
        for (int e = 0; e < E_EXP; ++e) acc[e] = fmaf(s, Wl[c * E_EXP + e], acc[e]);
    }

    // cross-lane reduce (64 lanes)
#pragma unroll
    for (int off = 32; off > 0; off >>= 1) {
#pragma unroll
        for (int e = 0; e < E_EXP; ++e) acc[e] += __shfl_xor(acc[e], off, 64);
    }
    if (lane == 0) {
#pragma unroll
        for (int e = 0; e < E_EXP; ++e) waveacc[w][e] = acc[e];
    }
    __syncthreads();

    if (t < E_EXP) {
        const int e = t;
        float logit = (waveacc[0][e] + waveacc[1][e] + waveacc[2][e] + waveacc[3][e]) * (1.f / HW)
                      + bg[e];
        // softmax across 16 lanes of wave 0
        float m = logit;
#pragma unroll
        for (int off = 8; off > 0; off >>= 1) m = fmaxf(m, __shfl_xor(m, off, 16));
        float ex = expf(logit - m);
        float s = ex;
#pragma unroll
        for (int off = 8; off > 0; off >>= 1) s += __shfl_xor(s, off, 16);
        int aidx = (logit == m) ? e : 1000;   // first-max tiebreak like jnp.argmax
#pragma unroll
        for (int off = 8; off > 0; off >>= 1) aidx = min(aidx, __shfl_xor(aidx, off, 16));

        const float prob = ex / s;
        atomicAdd(&ws[64 + e * 64 + (n & 63)], prob);   // density_2 partials
        if (e == 0) {
            atomicAdd(&ws[n & 63], m + logf(s));        // z-loss partials (logsumexp)
            ws[1088 + n] = 1.f / s;                     // expert_gate = max prob = e^0/s
            ((int*)ws)[5184 + n] = aidx;                // expert_index
        }
    }
}

__global__ __launch_bounds__(256) void k_scan(float* __restrict__ out, float* __restrict__ ws) {
    __shared__ int cnt[256 * 17];   // padded stride 17 vs bank conflicts
    __shared__ int run[256 * 17];
    const int t = threadIdx.x;
    const int* idx = (const int*)ws + 5184;
    const float* gate = ws + 1088;

#pragma unroll
    for (int e = 0; e < 17; ++e) cnt[t * 17 + e] = 0;
    // each thread owns 16 consecutive tokens
    const int n0 = t * 16;
    for (int j = 0; j < 16; ++j) cnt[t * 17 + idx[n0 + j]]++;
    __syncthreads();

    // inclusive Hillis-Steele scan over the 256 thread-chunks, 16 experts in parallel
    for (int step = 1; step < 256; step <<= 1) {
        int v[E_EXP];
        if (t >= step) {
#pragma unroll
            for (int e = 0; e < E_EXP; ++e) v[e] = cnt[(t - step) * 17 + e];
        }
        __syncthreads();
        if (t >= step) {
#pragma unroll
            for (int e = 0; e < E_EXP; ++e) cnt[t * 17 + e] += v[e];
        }
        __syncthreads();
    }

    // exclusive base for this chunk
#pragma unroll
    for (int e = 0; e < E_EXP; ++e) run[t * 17 + e] = (t == 0) ? 0 : cnt[(t - 1) * 17 + e];
    __syncthreads();

    // walk tokens in order, assign positions, scatter the nonzeros
    for (int j = 0; j < 16; ++j) {
        const int n = n0 + j;
        const int e = idx[n];
        const int pos = run[t * 17 + e]++;
        if (pos < CCAP) {
            const long long col = (long long)n * (E_EXP * CCAP) + e * CCAP + pos;
            out[col] = 1.0f;            // dispatch (combine > 0)
            out[NEC + col] = gate[n];   // combine
        }
    }

    if (t == 0) {
        float zs = 0.f;
        for (int j = 0; j < 64; ++j) zs += ws[j];
        float aux = 0.f;
        for (int e = 0; e < E_EXP; ++e) {
            float ps = 0.f;
            for (int j = 0; j < 64; ++j) ps += ws[64 + e * 64 + j];
            const float d1 = (float)cnt[255 * 17 + e] / (float)N_TOK;   // unmasked counts
            aux += d1 * (ps / (float)N_TOK);
        }
        out[2LL * NEC]     = zs / (float)N_TOK;   // z_loss
        out[2LL * NEC + 1] = aux * (float)E_EXP;  // aux_loss
    }
}

extern "C" void kernel_launch(void* const* d_in, const int* in_sizes, int n_in,
                              void* d_out, int out_size, void* d_ws, size_t ws_size,
                              hipStream_t stream) {
    const float* X  = (const float*)d_in[0];
    const float* Wg = (const float*)d_in[1];
    const float* bg = (const float*)d_in[2];
    float* out = (float*)d_out;
    float* ws  = (float*)d_ws;

    hipLaunchKernelGGL(k_zero,   dim3(2048), dim3(256), 0, stream, out, ws);
    hipLaunchKernelGGL(k_router, dim3(N_TOK), dim3(256), 0, stream, X, Wg, bg, ws);
    hipLaunchKernelGGL(k_scan,   dim3(1),    dim3(256), 0, stream, out, ws);
}

// Round 4
// 455.848 us; speedup vs baseline: 1.0326x; 1.0326x over previous
//
#include <hip/hip_runtime.h>
#include <math.h>

#define N_TOK 4096
#define E_EXP 16
#define CCAP  384
#define NEC   (N_TOK * E_EXP * CCAP)   // 25,165,824 elements per tensor

typedef float floatx4 __attribute__((ext_vector_type(4)));

// ws float layout (no zero-init needed — every slot fully overwritten each call):
//   [0, 4096)       : expert_gate per token
//   [4096, 8192)    : expert_index per token (int)
//   [8192, 12288)   : logsumexp per token
//   [12288, 77824)  : probs [n][e]  (4096 x 16)

__global__ __launch_bounds__(256) void k_main(const float* __restrict__ X,
                                              const float* __restrict__ Wg,
                                              const float* __restrict__ bg,
                                              float* __restrict__ out,
                                              float* __restrict__ ws) {
    __shared__ float Wl[64 * 16];       // 4 KB
    __shared__ float waveacc[4][16];
    const int t = threadIdx.x;
    const int n = blockIdx.x;

    // --- zero this block's 48 KB slice of out (2*NEC floats / 4096 blocks = 3072 float4) ---
    {
        floatx4* o4 = (floatx4*)out + (long long)n * 3072 + t;
        const floatx4 z = {0.f, 0.f, 0.f, 0.f};
#pragma unroll
        for (int j = 0; j < 12; ++j) __builtin_nontemporal_store(z, o4 + j * 256);
    }

    for (int j = t; j < 64 * 16; j += 256) Wl[j] = Wg[j];
    __syncthreads();

    const int w = t >> 6, lane = t & 63;
    const float4* Xv = (const float4*)(X + (long long)n * 16384);

    float acc[16];
#pragma unroll
    for (int e = 0; e < 16; ++e) acc[e] = 0.f;

    // iteration k: wave w reads channel c = 4k+w, 64 float4s coalesced (1 KB/instr)
#pragma unroll
    for (int k = 0; k < 16; ++k) {
        float4 v = Xv[k * 256 + w * 64 + lane];
        float s = (v.x + v.y) + (v.z + v.w);
        const int c = k * 4 + w;
#pragma unroll
        for (int e = 0; e < 16; ++e) acc[e] = fmaf(s, Wl[c * 16 + e], acc[e]);
    }

#pragma unroll
    for (int off = 32; off > 0; off >>= 1) {
#pragma unroll
        for (int e = 0; e < 16; ++e) acc[e] += __shfl_xor(acc[e], off, 64);
    }
    if (lane == 0) {
#pragma unroll
        for (int e = 0; e < 16; ++e) waveacc[w][e] = acc[e];
    }
    __syncthreads();

    if (t < 16) {
        const int e = t;
        float logit = (waveacc[0][e] + waveacc[1][e] + waveacc[2][e] + waveacc[3][e]) * (1.f / 256.f)
                      + bg[e];
        float m = logit;
#pragma unroll
        for (int off = 8; off > 0; off >>= 1) m = fmaxf(m, __shfl_xor(m, off, 16));
        float ex = expf(logit - m);
        float s = ex;
#pragma unroll
        for (int off = 8; off > 0; off >>= 1) s += __shfl_xor(s, off, 16);
        int aidx = (logit == m) ? e : 1000;   // first-max tiebreak like jnp.argmax
#pragma unroll
        for (int off = 8; off > 0; off >>= 1) aidx = min(aidx, __shfl_xor(aidx, off, 16));

        ws[12288 + n * 16 + e] = ex / s;      // probs
        if (e == 0) {
            ws[n] = 1.f / s;                  // expert_gate = max prob = e^0/s
            ((int*)ws)[4096 + n] = aidx;      // expert_index
            ws[8192 + n] = m + logf(s);       // logsumexp
        }
    }
}

__global__ __launch_bounds__(256) void k_scan(float* __restrict__ out, float* __restrict__ ws) {
    __shared__ int cnt[256 * 17];   // padded stride 17 vs bank conflicts
    __shared__ int run[256 * 17];
    __shared__ float wred[4][17];
    const int t = threadIdx.x;
    const int* idx = (const int*)ws + 4096;
    const float* gate = ws;
    const float* lse = ws + 8192;
    const float4* pv = (const float4*)(ws + 12288);
    const int n0 = t * 16;          // each thread owns 16 consecutive tokens

    // --- block-parallel partial sums for z-loss and density_2 ---
    float zp = 0.f;
    float pp[16];
#pragma unroll
    for (int e = 0; e < 16; ++e) pp[e] = 0.f;
    for (int j = 0; j < 16; ++j) {
        const int n = n0 + j;
        zp += lse[n];
#pragma unroll
        for (int q = 0; q < 4; ++q) {
            float4 v = pv[n * 4 + q];
            pp[q * 4 + 0] += v.x; pp[q * 4 + 1] += v.y;
            pp[q * 4 + 2] += v.z; pp[q * 4 + 3] += v.w;
        }
    }
    {
        const int w = t >> 6, lane = t & 63;
#pragma unroll
        for (int off = 32; off > 0; off >>= 1) {
            zp += __shfl_xor(zp, off, 64);
#pragma unroll
            for (int e = 0; e < 16; ++e) pp[e] += __shfl_xor(pp[e], off, 64);
        }
        if (lane == 0) {
            wred[w][16] = zp;
#pragma unroll
            for (int e = 0; e < 16; ++e) wred[w][e] = pp[e];
        }
    }

    // --- per-chunk expert counts ---
#pragma unroll
    for (int e = 0; e < 17; ++e) cnt[t * 17 + e] = 0;
    for (int j = 0; j < 16; ++j) cnt[t * 17 + idx[n0 + j]]++;
    __syncthreads();

    // inclusive Hillis-Steele scan over the 256 thread-chunks, 16 experts in parallel
    for (int step = 1; step < 256; step <<= 1) {
        int v[16];
        if (t >= step) {
#pragma unroll
            for (int e = 0; e < 16; ++e) v[e] = cnt[(t - step) * 17 + e];
        }
        __syncthreads();
        if (t >= step) {
#pragma unroll
            for (int e = 0; e < 16; ++e) cnt[t * 17 + e] += v[e];
        }
        __syncthreads();
    }

    // exclusive base for this chunk
#pragma unroll
    for (int e = 0; e < 16; ++e) run[t * 17 + e] = (t == 0) ? 0 : cnt[(t - 1) * 17 + e];
    __syncthreads();

    // walk tokens in order, assign positions, scatter the nonzeros
    for (int j = 0; j < 16; ++j) {
        const int n = n0 + j;
        const int e = idx[n];
        const int pos = run[t * 17 + e]++;
        if (pos < CCAP) {
            const long long col = (long long)n * (E_EXP * CCAP) + e * CCAP + pos;
            out[col] = 1.0f;            // dispatch (combine > 0)
            out[NEC + col] = gate[n];   // combine
        }
    }

    if (t == 0) {
        float zs = wred[0][16] + wred[1][16] + wred[2][16] + wred[3][16];
        float aux = 0.f;
        for (int e = 0; e < 16; ++e) {
            const float ps = wred[0][e] + wred[1][e] + wred[2][e] + wred[3][e];
            const float d1 = (float)cnt[255 * 17 + e] / (float)N_TOK;   // unmasked counts
            aux += d1 * (ps / (float)N_TOK);
        }
        out[2LL * NEC]     = zs / (float)N_TOK;   // z_loss
        out[2LL * NEC + 1] = aux * (float)E_EXP;  // aux_loss
    }
}

extern "C" void kernel_launch(void* const* d_in, const int* in_sizes, int n_in,
                              void* d_out, int out_size, void* d_ws, size_t ws_size,
                              hipStream_t stream) {
    const float* X  = (const float*)d_in[0];
    const float* Wg = (const float*)d_in[1];
    const float* bg = (const float*)d_in[2];
    float* out = (float*)d_out;
    float* ws  = (float*)d_ws;

    hipLaunchKernelGGL(k_main, dim3(N_TOK), dim3(256), 0, stream, X, Wg, bg, out, ws);
    hipLaunchKernelGGL(k_scan, dim3(1),     dim3(256), 0, stream, out, ws);
}